// Round 9
// baseline (606.789 us; speedup 1.0000x reference)
//
#include <hip/hip_runtime.h>
#include <hip/hip_fp16.h>
#include <cstdint>

#define T_STEPS 512
#define HDIM    256
#define ROWS    8
#define LN_EPS  1e-5f

typedef _Float16 half8   __attribute__((ext_vector_type(8)));
typedef _Float16 half4v  __attribute__((ext_vector_type(4)));
typedef float    float4v __attribute__((ext_vector_type(4)));
typedef float    float2v __attribute__((ext_vector_type(2)));
typedef int      int4v   __attribute__((ext_vector_type(4)));
typedef int      int2v   __attribute__((ext_vector_type(2)));

// R6: DS diet with SAFE cross-lane primitives. R5's absmax-0.74 failure is
// attributed to the hand-rolled permlane asm ("+v"(a),"+v"(b) with a==b can
// coalesce to one VGPR -> in-place swap scrambles rows). Here: the documented
// __builtin_amdgcn_permlane{16,32}_swap (two-result, compiler-managed), each
// guarded by __has_builtin with fallback to the R4-verified ds_swizzle /
// __shfl_xor. Numerics = R4 exactly (4 MFMAs/kt, all 3 fp16-pair terms).
// DS instr/wave/step: 21 -> ~13.5 (red consume 4->1 b128, xi 1->0.25 b32,
// crossbar DS -> VALU permlane when available).
#if __has_builtin(__builtin_amdgcn_permlane32_swap)
#define HAS_PL32 1
#else
#define HAS_PL32 0
#endif
#if __has_builtin(__builtin_amdgcn_permlane16_swap)
#define HAS_PL16 1
#else
#define HAS_PL16 0
#endif

struct __align__(16) Smem {
  _Float16 Bp[2][4096];     // 16384 B packed B fragments (double-buffered)
  float    gb[10][268];     // 10720 B gb[v][n] = tanh(v*we+be)@W + bu + beta@W
  float    wg[260];         // 1040 B  gamma @ W (deferred-LN mu term)
  float    wb[260];         // 1040 B  beta @ W
  float    red[2][8][20];   // 1280 B  [buf][row][wv*2+{0:S,1:Sq}], 8 slots
  int      xi[8][516];      // 16512 B clamped x indices (+4 pad for quad reads)
};

__device__ __forceinline__ float tanh_fast(float x) {
  float e = __expf(2.0f * x);
  float r = __builtin_amdgcn_rcpf(e + 1.0f);
  return fmaf(-2.0f, r, 1.0f);
}
// lane l -> l^8 (rotate-by-8 within each 16-lane row == xor 8), pure VALU
__device__ __forceinline__ float dpp_ror8(float v) {
  return __int_as_float(__builtin_amdgcn_mov_dpp(__float_as_int(v), 0x128, 0xf, 0xf, true));
}
// lane l -> l^16 (within 32-lane half), LDS crossbar, conflict-free (verified R1/R4)
__device__ __forceinline__ float swz_xor16(float v) {
  return __int_as_float(__builtin_amdgcn_ds_swizzle(__float_as_int(v), 0x401F));
}
// v[l] + v[l^16] in every lane
__device__ __forceinline__ float sum_xor16(float v) {
#if HAS_PL16
  int2v r2 = __builtin_amdgcn_permlane16_swap(__float_as_int(v), __float_as_int(v), false, false);
  return __int_as_float(r2[0]) + __int_as_float(r2[1]);
#else
  return v + swz_xor16(v);
#endif
}
// v[l] + v[l^32] in every lane
__device__ __forceinline__ float sum_xor32(float v) {
#if HAS_PL32
  int2v r2 = __builtin_amdgcn_permlane32_swap(__float_as_int(v), __float_as_int(v), false, false);
  return __int_as_float(r2[0]) + __int_as_float(r2[1]);
#else
  return v + __shfl_xor(v, 32, 64);
#endif
}

__global__ __launch_bounds__(512, 1)
void rnn_scan_kernel(const float* __restrict__ x,
                     const float* __restrict__ we,  const float* __restrict__ be,
                     const float* __restrict__ Wu,  const float* __restrict__ bu,
                     const float* __restrict__ gma, const float* __restrict__ bta,
                     const float* __restrict__ Wo,  const float* __restrict__ bo,
                     float* __restrict__ out)
{
  __shared__ Smem sm;
  const int tid = threadIdx.x;
  const int wv  = tid >> 6;        // wave 0..7, owns n in [32*wv, 32*wv+32)
  const int l   = tid & 63;
  const int q   = l >> 4;
  const int m   = l & 15;
  const int sel = m >> 3;          // 0: finalize nt=0 (hi cols), 1: nt=1
  const int r   = m & 7;           // batch row within tile
  const int r0  = blockIdx.x * ROWS;

  // ---- init 0: x -> clamped int indices in LDS (the ONLY x reads) ----
  for (int i = tid; i < ROWS * T_STEPS; i += 512) {
    const int rr = i >> 9, c = i & (T_STEPS - 1);
    int xv = (int)x[(size_t)(r0 + rr) * T_STEPS + c];
    xv = xv < 0 ? 0 : (xv > 9 ? 9 : xv);
    sm.xi[rr][c] = xv;
  }
  if (tid < ROWS) {                // 4-entry zero pad for the quad prefetch
    sm.xi[tid][512] = 0; sm.xi[tid][513] = 0;
    sm.xi[tid][514] = 0; sm.xi[tid][515] = 0;
  }

  // ---- init 1: embed-tanh table in (to-be-zeroed) Bp space ----
  float* et = reinterpret_cast<float*>(&sm.Bp[0][0]);   // 10240 B < 16384 B
  if (tid < HDIM) {
    const float wek = we[tid], bek = be[tid];
    #pragma unroll
    for (int v = 0; v < 10; ++v)
      et[v*HDIM + tid] = tanh_fast(fmaf((float)v, wek, bek));
  }
  __syncthreads();

  // ---- init 2: gb = et@W + bu ; wg = gamma@W ; wb = beta@W ----
  {
    const int g = tid >> 8;        // 0: v=0..4 + wg, 1: v=5..9 + wb
    const int n = tid & 255;
    float acc[5] = {0,0,0,0,0};
    float accx = 0.0f;
    const int vb = g * 5;
    for (int k = 0; k < HDIM; ++k) {
      const float wk = Wu[(size_t)k*HDIM + n];
      #pragma unroll
      for (int v = 0; v < 5; ++v) acc[v] = fmaf(et[(vb+v)*HDIM + k], wk, acc[v]);
      const float xk = g ? bta[k] : gma[k];
      accx = fmaf(xk, wk, accx);
    }
    const float bun = bu[n];
    #pragma unroll
    for (int v = 0; v < 5; ++v) sm.gb[vb+v][n] = acc[v] + bun;
    if (g == 0) sm.wg[n] = accx; else sm.wb[n] = accx;
  }
  __syncthreads();

  // ---- init 3: fold beta@W into gb; zero Bp (both bufs) and red ----
  if (tid < HDIM) {
    const float wbn = sm.wb[tid];
    #pragma unroll
    for (int v = 0; v < 10; ++v) sm.gb[v][tid] += wbn;
  }
  {
    uint32_t* p = reinterpret_cast<uint32_t*>(&sm.Bp[0][0]);
    for (int i = tid; i < 4096; i += 512) p[i] = 0u;      // 16 KB = both bufs
  }
  if (tid < 320) (&sm.red[0][0][0])[tid] = 0.0f;

  // ---- persistent W fragments: full K, this wave's two 16-wide n-tiles ----
  half8 Whi[2][8], Wlo[2][8];
  #pragma unroll
  for (int nt = 0; nt < 2; ++nt) {
    const int n = wv*32 + nt*16 + m;
    #pragma unroll
    for (int kt = 0; kt < 8; ++kt) {
      const int k0 = kt*32 + q*8;
      half8 hi, lo;
      #pragma unroll
      for (int j = 0; j < 8; ++j) {
        float v = Wu[(size_t)(k0 + j)*HDIM + n];           // L2-hot across blocks
        _Float16 h = (_Float16)v;
        hi[j] = h;
        lo[j] = (_Float16)((v - (float)h) * 2048.0f);
      }
      Whi[nt][kt] = hi; Wlo[nt][kt] = lo;
    }
  }
  const int n_sel = wv*32 + sel*16 + q*4;    // this lane's 4 finalized columns
  const float4v gmr = *reinterpret_cast<const float4v*>(&gma[n_sel]);
  __syncthreads();                            // wg/gb/xi ready, buffers zeroed
  const float4v wgr = *reinterpret_cast<const float4v*>(&sm.wg[n_sel]);

  const float c1 = 4.8828125e-4f;             // 2^-11
  const float* gbp = &sm.gb[0][n_sel];
  float4v th4;                                // last tanh outputs (epilogue)

  // per-lane constant LDS offsets (halves)
  const int rdoff = l * 8;                                        // B read base
  const int woff  = wv*512 + (2*sel + (q>>1))*128 + r*8 + (q&1)*4; // hi write; lo at +64

  // x-index quad prefetch (one b128 per 4 steps) + gb bias row one step ahead
  int4v xQ = *reinterpret_cast<const int4v*>(&sm.xi[r][0]);
  float4v gbv_n = *reinterpret_cast<const float4v*>(gbp + xQ[0]*268);

  for (int k = 0; k < T_STEPS/4; ++k) {
    const int4v xQn = *reinterpret_cast<const int4v*>(&sm.xi[r][k*4 + 4]);
    #pragma unroll
    for (int e = 0; e < 4; ++e) {
      const int rb = e & 1, wb = rb ^ 1;

      // issue red chunk read NOW, consume after the MFMA loop. Lane's q-group
      // reads chunk q (wave-partials 2q, 2q+1); cross-q lane sums finish it.
      const float4v pq = *reinterpret_cast<const float4v*>(&sm.red[rb][r][q*4]);

      const float4v gbv = gbv_n;                 // bias row for THIS step
      const int xv2 = (e < 3) ? xQ[e + 1] : xQn[0];   // compile-time select

      // MFMA phase: 1 lane-linear b128 read + 4 MFMAs per kt
      const _Float16* pbB = &sm.Bp[rb][rdoff];
      float4v d10, d11, d20, d21;
      d10 = 0.0f; d11 = 0.0f; d20 = 0.0f; d21 = 0.0f;
      #pragma unroll
      for (int kt = 0; kt < 8; ++kt) {
        const half8 b = *reinterpret_cast<const half8*>(pbB + kt*512);
        d10 = __builtin_amdgcn_mfma_f32_16x16x32_f16(Whi[0][kt], b, d10, 0, 0, 0);
        d11 = __builtin_amdgcn_mfma_f32_16x16x32_f16(Whi[1][kt], b, d11, 0, 0, 0);
        d20 = __builtin_amdgcn_mfma_f32_16x16x32_f16(Wlo[0][kt], b, d20, 0, 0, 0);
        d21 = __builtin_amdgcn_mfma_f32_16x16x32_f16(Wlo[1][kt], b, d21, 0, 0, 0);
      }

      // prefetch gb row for step t+1 (consumed next iteration)
      gbv_n = *reinterpret_cast<const float4v*>(gbp + xv2*268);

      // LN stats of th(t-1): chunk partial + cross-q sums (in MFMA shadow)
      float S  = pq[0] + pq[2];
      float Sq = pq[1] + pq[3];
      S  = sum_xor32(sum_xor16(S));
      Sq = sum_xor32(sum_xor16(Sq));
      const float mu  = S * (1.0f/256.0f);
      const float var = fmaf(Sq, 1.0f/256.0f, -mu*mu);
      const float rs  = __builtin_amdgcn_rsqf(var + LN_EPS);
      const float nrsmu = -rs * mu;
      const float rsc   = rs * c1;

      // tail: reassemble each output's 3 products from its two B columns.
      // sel=0 lanes (cols 0..7, hi products) finalize nt=0:
      //   local = rs*d10 + rsc*d20, partner sends rsc*d10 (=Whi0*lo_act).
      // sel=1 lanes (cols 8..15, lo products) finalize nt=1:
      //   local = rsc*d11 (=Whi1*lo_act), partner sends rs*d11 + rsc*d21.
      const float csA = sel ? rsc : rs;
      float4v sendv, locv;
      #pragma unroll
      for (int i2 = 0; i2 < 4; ++i2) {
        const float pA = sel ? d10[i2] : d11[i2];
        const float pB = sel ? 0.0f    : d21[i2];
        sendv[i2] = fmaf(csA, pA, rsc * pB);
        const float qA = sel ? d11[i2] : d10[i2];
        const float qB = sel ? 0.0f    : d20[i2];
        locv[i2]  = fmaf(csA, qA, rsc * qB);
      }
      float4v recv;
      #pragma unroll
      for (int i2 = 0; i2 < 4; ++i2) recv[i2] = dpp_ror8(sendv[i2]);

      float s = 0.0f, sq = 0.0f;
      half4v hi4, lo4;
      #pragma unroll
      for (int i2 = 0; i2 < 4; ++i2) {
        const float base = fmaf(nrsmu, wgr[i2], gbv[i2]);
        const float pre  = locv[i2] + recv[i2] + base;
        const float th   = tanh_fast(pre);
        th4[i2] = th; s += th; sq = fmaf(th, th, sq);
        const float g2 = th * gmr[i2];
        const _Float16 h16 = (_Float16)g2;
        hi4[i2] = h16;
        lo4[i2] = (_Float16)((g2 - (float)h16) * 2048.0f);
      }
      // full in-wave reduction: xor8 (DPP) + xor16 + xor32
      s  += dpp_ror8(s);  s  = sum_xor32(sum_xor16(s));
      sq += dpp_ror8(sq); sq = sum_xor32(sum_xor16(sq));

      _Float16* wp = &sm.Bp[wb][woff];
      *reinterpret_cast<half4v*>(wp)      = hi4;
      *reinterpret_cast<half4v*>(wp + 64) = lo4;
      if (l < 8) {
        float2v v2; v2[0] = s; v2[1] = sq;
        *reinterpret_cast<float2v*>(&sm.red[wb][l][wv*2]) = v2;
      }
      __syncthreads();                           // the ONLY barrier per step
    }
    xQ = xQn;
  }

  // ---- epilogue: final LN (stats in red[0]), h_final in gb space, out GEMM ----
  float mu, rs;
  {
    const float4v pq = *reinterpret_cast<const float4v*>(&sm.red[0][r][q*4]);
    float S  = pq[0] + pq[2];
    float Sq = pq[1] + pq[3];
    S  = sum_xor32(sum_xor16(S));
    Sq = sum_xor32(sum_xor16(Sq));
    mu = S * (1.0f/256.0f);
    const float var = fmaf(Sq, 1.0f/256.0f, -mu*mu);
    rs = __builtin_amdgcn_rsqf(var + LN_EPS);
  }
  float* hf = reinterpret_cast<float*>(&sm.gb[0][0]);   // gb dead after loop
  {
    const float4v btv = *reinterpret_cast<const float4v*>(&bta[n_sel]);
    float4v h4;
    #pragma unroll
    for (int e = 0; e < 4; ++e)
      h4[e] = fmaf((th4[e] - mu) * rs, gmr[e], btv[e]);
    *reinterpret_cast<float4v*>(&hf[r*260 + n_sel]) = h4;
  }
  __syncthreads();
  if (tid < ROWS*10) {
    const int rr = tid / 10, o = tid % 10;
    float acc = bo[o];
    #pragma unroll 4
    for (int n = 0; n < HDIM; ++n)
      acc = fmaf(hf[rr*260 + n], Wo[n*10 + o], acc);
    out[(size_t)(r0 + rr)*10 + o] = acc;
  }
}

extern "C" void kernel_launch(void* const* d_in, const int* in_sizes, int n_in,
                              void* d_out, int out_size, void* d_ws, size_t ws_size,
                              hipStream_t stream) {
  const float* x  = (const float*)d_in[0];
  const float* we = (const float*)d_in[1];
  const float* be = (const float*)d_in[2];
  const float* Wu = (const float*)d_in[3];
  const float* bu = (const float*)d_in[4];
  const float* ga = (const float*)d_in[5];
  const float* bt = (const float*)d_in[6];
  const float* Wo = (const float*)d_in[7];
  const float* bo = (const float*)d_in[8];
  const int B = in_sizes[0] / T_STEPS;          // 2048
  dim3 grid(B / ROWS), block(512);
  rnn_scan_kernel<<<grid, block, 0, stream>>>(x, we, be, Wu, bu, ga, bt, Wo, bo,
                                              (float*)d_out);
}